// Round 1
// baseline (108.178 us; speedup 1.0000x reference)
//
#include <hip/hip_runtime.h>
#include <hip/hip_bf16.h>
#include <math.h>

#define THREADS 512
#define BM 128
#define BN 128
#define DDIM 256
#define ROWBYTES 512            // DDIM * 2 bytes (bf16)

// LDS layout (dynamic):
//   Abf  @ 0        : 128*512 = 65536 B
//   Cbf  @ 65536    : 128*512 = 65536 B
//   e2   @ 131072   : 128 f32
//   c2   @ 131584   : 128 f32
//   lab  @ 132096   : 128 i32
//   red  @ 132608   : 8 f32
#define SMEM_BYTES 132672

typedef short bf16x8 __attribute__((ext_vector_type(8)));
typedef float f32x4  __attribute__((ext_vector_type(4)));

__device__ int g_lab_is64;

static __device__ __forceinline__ unsigned short f2bf(float x) {
    unsigned u = __builtin_bit_cast(unsigned, x);
    return (unsigned short)((u + 0x7fffu + ((u >> 16) & 1u)) >> 16);
}

// Detect whether the labels buffer is int64 (odd 32-bit words all zero) or int32.
__global__ void detect_labels_kernel(const unsigned* __restrict__ w, int nelem) {
    __shared__ unsigned red[256];
    unsigned acc = 0;
    for (int i = threadIdx.x; i < nelem / 2; i += 256) acc |= w[2 * i + 1];
    red[threadIdx.x] = acc;
    __syncthreads();
    for (int s = 128; s > 0; s >>= 1) {
        if (threadIdx.x < s) red[threadIdx.x] |= red[threadIdx.x + s];
        __syncthreads();
    }
    if (threadIdx.x == 0) g_lab_is64 = (red[0] == 0u) ? 1 : 0;
}

__global__ __launch_bounds__(THREADS) void loss_kernel(
    const float* __restrict__ emb, const float* __restrict__ cent,
    const int* __restrict__ labw, float* __restrict__ out,
    int nchunk, float invB)
{
    extern __shared__ char smem[];
    char*  Abf = smem;
    char*  Cbf = smem + 65536;
    float* e2  = (float*)(smem + 131072);
    float* c2  = (float*)(smem + 131584);
    int*   lab = (int*)(smem + 132096);
    float* red = (float*)(smem + 132608);

    const int tid  = threadIdx.x;
    const int lane = tid & 63;
    const int wid  = tid >> 6;
    const int row0 = blockIdx.x * BM;
    const int is64 = g_lab_is64;

    // ---- stage A tile (fp32 -> bf16, XOR-swizzled) + row norms e2 ----
    for (int j = 0; j < 16; ++j) {
        int f4 = tid + j * THREADS;          // 0..8191 ; row is wave-uniform
        int r  = f4 >> 6;
        int c4 = f4 & 63;
        float4 v = ((const float4*)emb)[(size_t)(row0 + r) * 64 + c4];
        ushort4 h;
        h.x = f2bf(v.x); h.y = f2bf(v.y); h.z = f2bf(v.z); h.w = f2bf(v.w);
        int off = (c4 * 8) ^ ((r & 7) << 4);
        *(ushort4*)(Abf + r * ROWBYTES + off) = h;
        float s = v.x * v.x + v.y * v.y + v.z * v.z + v.w * v.w;
        #pragma unroll
        for (int m = 32; m >= 1; m >>= 1) s += __shfl_xor(s, m, 64);
        if (lane == 0) e2[r] = s;
    }
    if (tid < BM) {
        int b = row0 + tid;
        lab[tid] = is64 ? labw[2 * b] : labw[b];   // little-endian low word
    }
    __syncthreads();

    const int wr  = wid >> 1;     // 0..3 : 32-row group
    const int wc  = wid & 1;      // 0..1 : 64-col group
    const int l15 = lane & 15;
    const int l16 = lane >> 4;
    const int swz = (l15 & 7) << 4;

    float e2v[2][4];
    int   labv[2][4];
    #pragma unroll
    for (int m = 0; m < 2; ++m)
        #pragma unroll
        for (int r = 0; r < 4; ++r) {
            int rr = wr * 32 + m * 16 + l16 * 4 + r;
            e2v[m][r] = e2[rr];
            labv[m][r] = lab[rr];
        }

    float fsum = 0.0f;

    for (int ch = 0; ch < nchunk; ++ch) {
        // ---- stage centroid chunk (fp32 -> bf16, swizzled) + c2 ----
        const float* cbase = cent + (size_t)ch * BN * DDIM;
        for (int j = 0; j < 16; ++j) {
            int f4 = tid + j * THREADS;
            int r  = f4 >> 6;
            int c4 = f4 & 63;
            float4 v = ((const float4*)cbase)[(size_t)r * 64 + c4];
            ushort4 h;
            h.x = f2bf(v.x); h.y = f2bf(v.y); h.z = f2bf(v.z); h.w = f2bf(v.w);
            int off = (c4 * 8) ^ ((r & 7) << 4);
            *(ushort4*)(Cbf + r * ROWBYTES + off) = h;
            float s = v.x * v.x + v.y * v.y + v.z * v.z + v.w * v.w;
            #pragma unroll
            for (int m = 32; m >= 1; m >>= 1) s += __shfl_xor(s, m, 64);
            if (lane == 0) c2[r] = s;
        }
        __syncthreads();

        f32x4 acc[2][4];
        #pragma unroll
        for (int m = 0; m < 2; ++m)
            #pragma unroll
            for (int n = 0; n < 4; ++n)
                acc[m][n] = (f32x4){0.0f, 0.0f, 0.0f, 0.0f};

        #pragma unroll
        for (int kk = 0; kk < 8; ++kk) {
            int kb = kk * 64 + l16 * 16;
            bf16x8 a[2], b[4];
            #pragma unroll
            for (int m = 0; m < 2; ++m) {
                int rr = wr * 32 + m * 16 + l15;
                a[m] = *(const bf16x8*)(Abf + rr * ROWBYTES + (kb ^ swz));
            }
            #pragma unroll
            for (int n = 0; n < 4; ++n) {
                int rr = wc * 64 + n * 16 + l15;
                b[n] = *(const bf16x8*)(Cbf + rr * ROWBYTES + (kb ^ swz));
            }
            #pragma unroll
            for (int m = 0; m < 2; ++m)
                #pragma unroll
                for (int n = 0; n < 4; ++n)
                    acc[m][n] = __builtin_amdgcn_mfma_f32_16x16x32_bf16(a[m], b[n], acc[m][n], 0, 0, 0);
        }

        // ---- epilogue ----
        float c2v[4]; int colg[4];
        #pragma unroll
        for (int n = 0; n < 4; ++n) {
            int cl = wc * 64 + n * 16 + l15;
            c2v[n] = c2[cl];
            colg[n] = ch * BN + cl;
        }
        unsigned need = 0;
        #pragma unroll
        for (int m = 0; m < 2; ++m)
            #pragma unroll
            for (int n = 0; n < 4; ++n)
                #pragma unroll
                for (int r = 0; r < 4; ++r) {
                    float d2 = fmaf(-2.0f, acc[m][n][r], e2v[m][r] + c2v[n]);
                    d2 = fmaxf(d2, 0.0f);
                    bool isp = (colg[n] == labv[m][r]);
                    fsum += isp ? d2 : 0.0f;
                    need |= (unsigned)((!isp) & (d2 < 1.0f)) << (m * 16 + n * 4 + r);
                }
        if (__any(need != 0)) {   // rare: only when a distance < MARGIN exists
            #pragma unroll
            for (int m = 0; m < 2; ++m)
                #pragma unroll
                for (int n = 0; n < 4; ++n)
                    #pragma unroll
                    for (int r = 0; r < 4; ++r)
                        if ((need >> (m * 16 + n * 4 + r)) & 1u) {
                            float d2 = fmaf(-2.0f, acc[m][n][r], e2v[m][r] + c2v[n]);
                            d2 = fmaxf(d2, 0.0f);
                            float t = 1.0f - sqrtf(d2);
                            fsum += t * t;
                        }
        }
        __syncthreads();   // before next chunk overwrites Cbf/c2
    }

    // ---- block reduction + global atomic ----
    #pragma unroll
    for (int m = 32; m >= 1; m >>= 1) fsum += __shfl_xor(fsum, m, 64);
    if (lane == 0) red[wid] = fsum;
    __syncthreads();
    if (tid == 0) {
        float t = 0.0f;
        #pragma unroll
        for (int w = 0; w < 8; ++w) t += red[w];
        atomicAdd(out, t * invB);
    }
}

extern "C" void kernel_launch(void* const* d_in, const int* in_sizes, int n_in,
                              void* d_out, int out_size, void* d_ws, size_t ws_size,
                              hipStream_t stream) {
    const float* emb  = (const float*)d_in[0];
    const float* cent = (const float*)d_in[1];
    const int*   labw = (const int*)d_in[2];
    float* out = (float*)d_out;

    const int B = in_sizes[0] / DDIM;   // 32768
    const int K = in_sizes[1] / DDIM;   // 1024
    const int nchunk = K / BN;          // 8

    hipMemsetAsync(d_out, 0, (size_t)out_size * sizeof(float), stream);
    detect_labels_kernel<<<1, 256, 0, stream>>>((const unsigned*)d_in[2], in_sizes[2]);

    hipFuncSetAttribute(reinterpret_cast<const void*>(loss_kernel),
                        hipFuncAttributeMaxDynamicSharedMemorySize, SMEM_BYTES);

    loss_kernel<<<B / BM, THREADS, SMEM_BYTES, stream>>>(
        emb, cent, labw, out, nchunk, 1.0f / (float)B);
}

// Round 2
// 80.777 us; speedup vs baseline: 1.3392x; 1.3392x over previous
//
#include <hip/hip_runtime.h>
#include <hip/hip_bf16.h>
#include <math.h>

typedef short bf16x8 __attribute__((ext_vector_type(8)));
typedef float f32x4  __attribute__((ext_vector_type(4)));

static __device__ __forceinline__ unsigned short f2bf(float x) {
    unsigned u = __builtin_bit_cast(unsigned, x);
    return (unsigned short)((u + 0x7fffu + ((u >> 16) & 1u)) >> 16);
}

static __device__ __forceinline__ bf16x8 pack8(float4 u0, float4 u1) {
    bf16x8 f;
    f[0] = (short)f2bf(u0.x); f[1] = (short)f2bf(u0.y);
    f[2] = (short)f2bf(u0.z); f[3] = (short)f2bf(u0.w);
    f[4] = (short)f2bf(u1.x); f[5] = (short)f2bf(u1.y);
    f[6] = (short)f2bf(u1.z); f[7] = (short)f2bf(u1.w);
    return f;
}

static __device__ __forceinline__ void async_cp16(const void* gsrc, void* ldsdst) {
    __builtin_amdgcn_global_load_lds(
        (const __attribute__((address_space(1))) void*)gsrc,
        (__attribute__((address_space(3))) void*)ldsdst, 16, 0, 0);
}

// ---------------- label width detection (parallel, flag in ws) ----------------
__global__ void detect_kernel(const unsigned* __restrict__ w, int nelem,
                              unsigned* __restrict__ flag) {
    unsigned acc = 0;
    for (int i = blockIdx.x * blockDim.x + threadIdx.x; i < nelem / 2;
         i += gridDim.x * blockDim.x)
        acc |= w[2 * i + 1];
    #pragma unroll
    for (int m = 32; m >= 1; m >>= 1) acc |= __shfl_xor(acc, m, 64);
    if ((threadIdx.x & 63) == 0 && acc) atomicOr(flag, 1u);
}

// ---------------- centroid pre-pass: bf16 fragment image + c2 + c2min --------
// image[cb][k][lane][j] = cent[cb*16 + (lane&15)][k*32 + (lane>>4)*8 + j]
__global__ void prep_cent_kernel(const float* __restrict__ cent,
                                 char* __restrict__ Cimg,
                                 float* __restrict__ c2g,
                                 unsigned* __restrict__ c2min) {
    const int lane = threadIdx.x & 63, wid = threadIdx.x >> 6;
    const int cb = blockIdx.x * 4 + wid;          // colblk of 16 centroids
    const int r = cb * 16 + (lane & 15);
    const int q = lane >> 4;
    const float4* C4 = (const float4*)cent;
    float s = 0.0f;
    #pragma unroll
    for (int k = 0; k < 8; ++k) {
        int fidx = r * 64 + k * 8 + q * 2;
        float4 u0 = C4[fidx], u1 = C4[fidx + 1];
        *(bf16x8*)(Cimg + ((size_t)(cb * 8 + k) * 64 + lane) * 16) = pack8(u0, u1);
        s += u0.x*u0.x + u0.y*u0.y + u0.z*u0.z + u0.w*u0.w
           + u1.x*u1.x + u1.y*u1.y + u1.z*u1.z + u1.w*u1.w;
    }
    s += __shfl_xor(s, 16, 64);
    s += __shfl_xor(s, 32, 64);
    if (lane < 16) c2g[cb * 16 + lane] = s;
    float mn = s;
    #pragma unroll
    for (int m = 8; m >= 1; m >>= 1) mn = fminf(mn, __shfl_xor(mn, m, 64));
    if (lane == 0) atomicMin((int*)c2min, __float_as_int(mn));
}

// ---------------- embedding pre-pass: bf16 fragment image + e2 + e2min + pos --
// image[rb][k][lane][j] = emb[rb*16 + (lane&15)][k*32 + (lane>>4)*8 + j]
// Also accumulates (1/B)*sum_b [ d2(b,lab_b) - relu(1-d_lab)^2 ]  (exact fp32).
__global__ void prep_emb_kernel(const float* __restrict__ emb,
                                const float* __restrict__ cent,
                                const int* __restrict__ labw,
                                const unsigned* __restrict__ flag,
                                char* __restrict__ Abf,
                                float* __restrict__ e2g,
                                unsigned* __restrict__ e2min,
                                float* __restrict__ out, float invB) {
    const int lane = threadIdx.x & 63, wid = threadIdx.x >> 6;
    const int rb = blockIdx.x * 4 + wid;          // rowblk of 16 rows
    const int r = rb * 16 + (lane & 15);
    const int q = lane >> 4;
    const int is64 = (*flag == 0u);
    const int lab = is64 ? labw[2 * r] : labw[r];
    const float4* E4 = (const float4*)emb;
    const float4* C4 = (const float4*)cent;
    float s = 0.0f, dot = 0.0f, c2l = 0.0f;
    #pragma unroll
    for (int k = 0; k < 8; ++k) {
        int fo = k * 8 + q * 2;
        float4 u0 = E4[r * 64 + fo], u1 = E4[r * 64 + fo + 1];
        *(bf16x8*)(Abf + ((size_t)(rb * 8 + k) * 64 + lane) * 16) = pack8(u0, u1);
        s += u0.x*u0.x + u0.y*u0.y + u0.z*u0.z + u0.w*u0.w
           + u1.x*u1.x + u1.y*u1.y + u1.z*u1.z + u1.w*u1.w;
        float4 v0 = C4[lab * 64 + fo], v1 = C4[lab * 64 + fo + 1];
        dot += u0.x*v0.x + u0.y*v0.y + u0.z*v0.z + u0.w*v0.w
             + u1.x*v1.x + u1.y*v1.y + u1.z*v1.z + u1.w*v1.w;
        c2l += v0.x*v0.x + v0.y*v0.y + v0.z*v0.z + v0.w*v0.w
             + v1.x*v1.x + v1.y*v1.y + v1.z*v1.z + v1.w*v1.w;
    }
    s += __shfl_xor(s, 16, 64);  s += __shfl_xor(s, 32, 64);
    dot += __shfl_xor(dot, 16, 64); dot += __shfl_xor(dot, 32, 64);
    c2l += __shfl_xor(c2l, 16, 64); c2l += __shfl_xor(c2l, 32, 64);
    if (lane < 16) e2g[rb * 16 + lane] = s;
    float mn = s;
    #pragma unroll
    for (int m = 8; m >= 1; m >>= 1) mn = fminf(mn, __shfl_xor(mn, m, 64));
    float d2 = fmaxf(s + c2l - 2.0f * dot, 0.0f);
    float pos = d2;
    if (d2 < 1.0f) { float t = 1.0f - sqrtf(d2); pos -= t * t; }
    #pragma unroll
    for (int m = 8; m >= 1; m >>= 1) pos += __shfl_xor(pos, m, 64);
    if (lane == 0) {
        atomicMin((int*)e2min, __float_as_int(mn));
        atomicAdd(out, pos * invB);
    }
}

// ---------------- main kernel: A in regs, B double-buffered LDS, MFMA --------
#define CHUNK_BYTES 65536
#define MAIN_SMEM (2 * CHUNK_BYTES + 64)

__global__ __launch_bounds__(512, 2) void main_kernel(
    const char* __restrict__ Abf, const char* __restrict__ Cimg,
    const float* __restrict__ e2g, const float* __restrict__ c2g,
    const unsigned* __restrict__ e2minp, const unsigned* __restrict__ c2minp,
    float* __restrict__ out, int nchunk, float invB) {
    extern __shared__ char smem[];
    char* Bb0 = smem;
    char* Bb1 = smem + CHUNK_BYTES;
    float* red = (float*)(smem + 2 * CHUNK_BYTES);

    const int tid = threadIdx.x, lane = tid & 63, wid = tid >> 6;
    const int wr = wid >> 2, wc = wid & 3;      // 2x4 wave grid, wave tile 64x32
    const int row0 = blockIdx.x * 128;
    const float thresh =
        0.5f * (__uint_as_float(*e2minp) + __uint_as_float(*c2minp) - 1.0f);

    // stage chunk 0 (async, direct to LDS)
    #pragma unroll
    for (int i = 0; i < 8; ++i)
        async_cp16(Cimg + i * 8192 + tid * 16, Bb0 + i * 8192 + wid * 1024);

    // load this wave's A fragments for full K=256 (held across all chunks)
    bf16x8 a[4][8];
    const char* Ab = Abf + (size_t)(row0 / 16 + wr * 4) * 8192;
    #pragma unroll
    for (int m = 0; m < 4; ++m)
        #pragma unroll
        for (int k = 0; k < 8; ++k)
            a[m][k] = *(const bf16x8*)(Ab + m * 8192 + (k * 64 + lane) * 16);

    float fsum = 0.0f;
    asm volatile("s_waitcnt vmcnt(0)" ::: "memory");
    __builtin_amdgcn_s_barrier();

    for (int ch = 0; ch < nchunk; ++ch) {
        const char* Bcur = (ch & 1) ? Bb1 : Bb0;
        char* Bnxt = (ch & 1) ? Bb0 : Bb1;
        if (ch + 1 < nchunk) {
            const char* src = Cimg + (size_t)(ch + 1) * CHUNK_BYTES;
            #pragma unroll
            for (int i = 0; i < 8; ++i)
                async_cp16(src + i * 8192 + tid * 16, Bnxt + i * 8192 + wid * 1024);
        }

        f32x4 acc[4][2];
        #pragma unroll
        for (int m = 0; m < 4; ++m) {
            acc[m][0] = (f32x4){0.0f, 0.0f, 0.0f, 0.0f};
            acc[m][1] = (f32x4){0.0f, 0.0f, 0.0f, 0.0f};
        }
        const char* Bw = Bcur + wc * 16384 + lane * 16;
        #pragma unroll
        for (int k = 0; k < 8; ++k) {
            bf16x8 b0 = *(const bf16x8*)(Bw + k * 1024);
            bf16x8 b1 = *(const bf16x8*)(Bw + 8192 + k * 1024);
            #pragma unroll
            for (int m = 0; m < 4; ++m) {
                acc[m][0] = __builtin_amdgcn_mfma_f32_16x16x32_bf16(a[m][k], b0, acc[m][0], 0, 0, 0);
                acc[m][1] = __builtin_amdgcn_mfma_f32_16x16x32_bf16(a[m][k], b1, acc[m][1], 0, 0, 0);
            }
        }

        // conservative screen: any dot big enough that d2 could be < 1?
        float mx = -3.0e38f;
        #pragma unroll
        for (int m = 0; m < 4; ++m)
            #pragma unroll
            for (int n = 0; n < 2; ++n)
                #pragma unroll
                for (int r = 0; r < 4; ++r)
                    mx = fmaxf(mx, acc[m][n][r]);
        if (__any(mx > thresh)) {   // rare/never: exact per-element slow path
            #pragma unroll
            for (int m = 0; m < 4; ++m)
                #pragma unroll
                for (int n = 0; n < 2; ++n)
                    #pragma unroll
                    for (int r = 0; r < 4; ++r) {
                        float dv = acc[m][n][r];
                        int rowg = row0 + wr * 64 + m * 16 + (lane >> 4) * 4 + r;
                        int colg = ch * 128 + wc * 32 + n * 16 + (lane & 15);
                        float d2 = fmaxf(e2g[rowg] + c2g[colg] - 2.0f * dv, 0.0f);
                        if (d2 < 1.0f) { float t = 1.0f - sqrtf(d2); fsum += t * t; }
                    }
        }
        asm volatile("s_waitcnt vmcnt(0)" ::: "memory");
        __builtin_amdgcn_s_barrier();
    }

    #pragma unroll
    for (int m = 32; m >= 1; m >>= 1) fsum += __shfl_xor(fsum, m, 64);
    if (lane == 0) red[wid] = fsum;
    __syncthreads();
    if (tid == 0) {
        float t = 0.0f;
        #pragma unroll
        for (int w = 0; w < 8; ++w) t += red[w];
        atomicAdd(out, t * invB);
    }
}

// ======================= fallback (round-1, verified) ========================
#define FB_THREADS 512
#define FB_SMEM 132672
__device__ int g_lab_is64;

__global__ void fb_detect_kernel(const unsigned* __restrict__ w, int nelem) {
    __shared__ unsigned red[256];
    unsigned acc = 0;
    for (int i = threadIdx.x; i < nelem / 2; i += 256) acc |= w[2 * i + 1];
    red[threadIdx.x] = acc;
    __syncthreads();
    for (int s = 128; s > 0; s >>= 1) {
        if (threadIdx.x < s) red[threadIdx.x] |= red[threadIdx.x + s];
        __syncthreads();
    }
    if (threadIdx.x == 0) g_lab_is64 = (red[0] == 0u) ? 1 : 0;
}

__global__ __launch_bounds__(FB_THREADS) void fb_loss_kernel(
    const float* __restrict__ emb, const float* __restrict__ cent,
    const int* __restrict__ labw, float* __restrict__ out,
    int nchunk, float invB) {
    extern __shared__ char smem[];
    char* Abf = smem;
    char* Cbf = smem + 65536;
    float* e2 = (float*)(smem + 131072);
    float* c2 = (float*)(smem + 131584);
    int* lab = (int*)(smem + 132096);
    float* red = (float*)(smem + 132608);

    const int tid = threadIdx.x, lane = tid & 63, wid = tid >> 6;
    const int row0 = blockIdx.x * 128;
    const int is64 = g_lab_is64;

    for (int j = 0; j < 16; ++j) {
        int f4 = tid + j * FB_THREADS;
        int r = f4 >> 6, c4 = f4 & 63;
        float4 v = ((const float4*)emb)[(size_t)(row0 + r) * 64 + c4];
        ushort4 h;
        h.x = f2bf(v.x); h.y = f2bf(v.y); h.z = f2bf(v.z); h.w = f2bf(v.w);
        int off = (c4 * 8) ^ ((r & 7) << 4);
        *(ushort4*)(Abf + r * 512 + off) = h;
        float s = v.x*v.x + v.y*v.y + v.z*v.z + v.w*v.w;
        #pragma unroll
        for (int m = 32; m >= 1; m >>= 1) s += __shfl_xor(s, m, 64);
        if (lane == 0) e2[r] = s;
    }
    if (tid < 128) {
        int b = row0 + tid;
        lab[tid] = is64 ? labw[2 * b] : labw[b];
    }
    __syncthreads();

    const int wr = wid >> 1, wc = wid & 1;
    const int l15 = lane & 15, l16 = lane >> 4;
    const int swz = (l15 & 7) << 4;

    float e2v[2][4]; int labv[2][4];
    #pragma unroll
    for (int m = 0; m < 2; ++m)
        #pragma unroll
        for (int r = 0; r < 4; ++r) {
            int rr = wr * 32 + m * 16 + l16 * 4 + r;
            e2v[m][r] = e2[rr]; labv[m][r] = lab[rr];
        }

    float fsum = 0.0f;
    for (int ch = 0; ch < nchunk; ++ch) {
        const float* cbase = cent + (size_t)ch * 128 * 256;
        for (int j = 0; j < 16; ++j) {
            int f4 = tid + j * FB_THREADS;
            int r = f4 >> 6, c4 = f4 & 63;
            float4 v = ((const float4*)cbase)[(size_t)r * 64 + c4];
            ushort4 h;
            h.x = f2bf(v.x); h.y = f2bf(v.y); h.z = f2bf(v.z); h.w = f2bf(v.w);
            int off = (c4 * 8) ^ ((r & 7) << 4);
            *(ushort4*)(Cbf + r * 512 + off) = h;
            float s = v.x*v.x + v.y*v.y + v.z*v.z + v.w*v.w;
            #pragma unroll
            for (int m = 32; m >= 1; m >>= 1) s += __shfl_xor(s, m, 64);
            if (lane == 0) c2[r] = s;
        }
        __syncthreads();

        f32x4 acc[2][4];
        #pragma unroll
        for (int m = 0; m < 2; ++m)
            #pragma unroll
            for (int n = 0; n < 4; ++n) acc[m][n] = (f32x4){0, 0, 0, 0};

        #pragma unroll
        for (int kk = 0; kk < 8; ++kk) {
            int kb = kk * 64 + l16 * 16;
            bf16x8 a[2], b[4];
            #pragma unroll
            for (int m = 0; m < 2; ++m)
                a[m] = *(const bf16x8*)(Abf + (wr * 32 + m * 16 + l15) * 512 + (kb ^ swz));
            #pragma unroll
            for (int n = 0; n < 4; ++n)
                b[n] = *(const bf16x8*)(Cbf + (wc * 64 + n * 16 + l15) * 512 + (kb ^ swz));
            #pragma unroll
            for (int m = 0; m < 2; ++m)
                #pragma unroll
                for (int n = 0; n < 4; ++n)
                    acc[m][n] = __builtin_amdgcn_mfma_f32_16x16x32_bf16(a[m], b[n], acc[m][n], 0, 0, 0);
        }

        float c2v[4]; int colg[4];
        #pragma unroll
        for (int n = 0; n < 4; ++n) {
            int cl = wc * 64 + n * 16 + l15;
            c2v[n] = c2[cl]; colg[n] = ch * 128 + cl;
        }
        unsigned need = 0;
        #pragma unroll
        for (int m = 0; m < 2; ++m)
            #pragma unroll
            for (int n = 0; n < 4; ++n)
                #pragma unroll
                for (int r = 0; r < 4; ++r) {
                    float d2 = fmaf(-2.0f, acc[m][n][r], e2v[m][r] + c2v[n]);
                    d2 = fmaxf(d2, 0.0f);
                    bool isp = (colg[n] == labv[m][r]);
                    fsum += isp ? d2 : 0.0f;
                    need |= (unsigned)((!isp) & (d2 < 1.0f)) << (m * 16 + n * 4 + r);
                }
        if (__any(need != 0)) {
            #pragma unroll
            for (int m = 0; m < 2; ++m)
                #pragma unroll
                for (int n = 0; n < 4; ++n)
                    #pragma unroll
                    for (int r = 0; r < 4; ++r)
                        if ((need >> (m * 16 + n * 4 + r)) & 1u) {
                            float d2 = fmaf(-2.0f, acc[m][n][r], e2v[m][r] + c2v[n]);
                            d2 = fmaxf(d2, 0.0f);
                            float t = 1.0f - sqrtf(d2);
                            fsum += t * t;
                        }
        }
        __syncthreads();
    }
    #pragma unroll
    for (int m = 32; m >= 1; m >>= 1) fsum += __shfl_xor(fsum, m, 64);
    if (lane == 0) red[wid] = fsum;
    __syncthreads();
    if (tid == 0) {
        float t = 0.0f;
        #pragma unroll
        for (int w = 0; w < 8; ++w) t += red[w];
        atomicAdd(out, t * invB);
    }
}

// =============================================================================
extern "C" void kernel_launch(void* const* d_in, const int* in_sizes, int n_in,
                              void* d_out, int out_size, void* d_ws, size_t ws_size,
                              hipStream_t stream) {
    const float* emb = (const float*)d_in[0];
    const float* cent = (const float*)d_in[1];
    const int* labw = (const int*)d_in[2];
    float* out = (float*)d_out;

    const int B = in_sizes[0] / 256;
    const int K = in_sizes[1] / 256;
    const int nchunk = K / 128;
    const float invB = 1.0f / (float)B;

    hipMemsetAsync(d_out, 0, (size_t)out_size * sizeof(float), stream);

    char* ws = (char*)d_ws;
    const size_t off_flag = 0, off_c2min = 64, off_e2min = 128, off_c2 = 256;
    const size_t off_e2 = 8192;
    const size_t off_cimg = off_e2 + (size_t)B * 4;
    const size_t off_abf = (off_cimg + (size_t)K * 512 + 1023) & ~(size_t)1023;
    const size_t req = off_abf + (size_t)B * 512;

    if (ws_size >= req) {
        hipMemsetAsync(ws + off_flag, 0, 4, stream);
        hipMemsetAsync(ws + off_c2min, 0x7F, 4, stream);
        hipMemsetAsync(ws + off_e2min, 0x7F, 4, stream);

        detect_kernel<<<32, 256, 0, stream>>>((const unsigned*)d_in[2], in_sizes[2],
                                              (unsigned*)(ws + off_flag));
        prep_cent_kernel<<<K / 64, 256, 0, stream>>>(
            cent, ws + off_cimg, (float*)(ws + off_c2), (unsigned*)(ws + off_c2min));
        prep_emb_kernel<<<B / 64, 256, 0, stream>>>(
            emb, cent, labw, (const unsigned*)(ws + off_flag), ws + off_abf,
            (float*)(ws + off_e2), (unsigned*)(ws + off_e2min), out, invB);

        hipFuncSetAttribute(reinterpret_cast<const void*>(main_kernel),
                            hipFuncAttributeMaxDynamicSharedMemorySize, MAIN_SMEM);
        main_kernel<<<B / 128, 512, MAIN_SMEM, stream>>>(
            ws + off_abf, ws + off_cimg, (const float*)(ws + off_e2),
            (const float*)(ws + off_c2), (const unsigned*)(ws + off_e2min),
            (const unsigned*)(ws + off_c2min), out, nchunk, invB);
    } else {
        fb_detect_kernel<<<1, 256, 0, stream>>>((const unsigned*)d_in[2], in_sizes[2]);
        hipFuncSetAttribute(reinterpret_cast<const void*>(fb_loss_kernel),
                            hipFuncAttributeMaxDynamicSharedMemorySize, FB_SMEM);
        fb_loss_kernel<<<B / 128, FB_THREADS, FB_SMEM, stream>>>(
            emb, cent, labw, out, nchunk, invB);
    }
}

// Round 3
// 73.941 us; speedup vs baseline: 1.4630x; 1.0924x over previous
//
#include <hip/hip_runtime.h>
#include <hip/hip_bf16.h>
#include <math.h>

typedef short bf16x8 __attribute__((ext_vector_type(8)));
typedef float f32x4  __attribute__((ext_vector_type(4)));

static __device__ __forceinline__ unsigned short f2bf(float x) {
    unsigned u = __builtin_bit_cast(unsigned, x);
    return (unsigned short)((u + 0x7fffu + ((u >> 16) & 1u)) >> 16);
}

static __device__ __forceinline__ bf16x8 pack8(float4 u0, float4 u1) {
    bf16x8 f;
    f[0] = (short)f2bf(u0.x); f[1] = (short)f2bf(u0.y);
    f[2] = (short)f2bf(u0.z); f[3] = (short)f2bf(u0.w);
    f[4] = (short)f2bf(u1.x); f[5] = (short)f2bf(u1.y);
    f[6] = (short)f2bf(u1.z); f[7] = (short)f2bf(u1.w);
    return f;
}

static __device__ __forceinline__ void async_cp16(const void* gsrc, void* ldsdst) {
    __builtin_amdgcn_global_load_lds(
        (const __attribute__((address_space(1))) void*)gsrc,
        (__attribute__((address_space(3))) void*)ldsdst, 16, 0, 0);
}

// ---- init+detect: zero out, init minima, classify label width (1 block) ----
__global__ void init_detect_kernel(const unsigned* __restrict__ w, int nelem,
                                   unsigned* __restrict__ flag,      // 1 = int32
                                   unsigned* __restrict__ e2min,
                                   unsigned* __restrict__ c2min,
                                   float* __restrict__ out, int out_size) {
    const int tid = threadIdx.x;            // 64 threads
    int npairs = nelem / 2; if (npairs > 4096) npairs = 4096;
    unsigned acc = 0;
    for (int i = tid; i < npairs; i += 64) acc |= w[2 * i + 1];
    #pragma unroll
    for (int m = 32; m >= 1; m >>= 1) acc |= __shfl_xor(acc, m, 64);
    if (tid == 0) {
        *flag = (acc != 0u) ? 1u : 0u;
        *e2min = 0x7F7F7F7Fu;
        *c2min = 0x7F7F7F7Fu;
    }
    for (int i = tid; i < out_size; i += 64) out[i] = 0.0f;
}

// ---- fused pre-pass: blocks [0,ncb) centroids, blocks [ncb, ...) embeddings --
// image layout: img[b16][k][lane][j] = src[b16*16 + (lane&15)][k*32 + (lane>>4)*8 + j]
__global__ __launch_bounds__(256) void prep_kernel(
    const float* __restrict__ emb, const float* __restrict__ cent,
    const int* __restrict__ labw, const unsigned* __restrict__ flag,
    char* __restrict__ Cimg, float* __restrict__ c2g, unsigned* __restrict__ c2min,
    char* __restrict__ Abf, float* __restrict__ e2g, unsigned* __restrict__ e2min,
    float* __restrict__ out, float invB, int ncb) {
    const int lane = threadIdx.x & 63, wid = threadIdx.x >> 6;
    const int q = lane >> 4;

    if ((int)blockIdx.x < ncb) {
        // ---------------- centroid part ----------------
        const int cb = blockIdx.x * 4 + wid;
        const int r = cb * 16 + (lane & 15);
        const float4* C4 = (const float4*)cent;
        float s = 0.0f;
        #pragma unroll
        for (int k = 0; k < 8; ++k) {
            int fidx = r * 64 + k * 8 + q * 2;
            float4 u0 = C4[fidx], u1 = C4[fidx + 1];
            *(bf16x8*)(Cimg + ((size_t)(cb * 8 + k) * 64 + lane) * 16) = pack8(u0, u1);
            s += u0.x*u0.x + u0.y*u0.y + u0.z*u0.z + u0.w*u0.w
               + u1.x*u1.x + u1.y*u1.y + u1.z*u1.z + u1.w*u1.w;
        }
        s += __shfl_xor(s, 16, 64);
        s += __shfl_xor(s, 32, 64);
        if (lane < 16) c2g[cb * 16 + lane] = s;
        float mn = s;
        #pragma unroll
        for (int m = 8; m >= 1; m >>= 1) mn = fminf(mn, __shfl_xor(mn, m, 64));
        if (lane == 0) atomicMin((int*)c2min, __float_as_int(mn));
    } else {
        // ---------------- embedding part ----------------
        const int rb = ((int)blockIdx.x - ncb) * 4 + wid;
        const int r = rb * 16 + (lane & 15);
        const int is32 = (*flag != 0u);
        const int lab = is32 ? labw[r] : labw[2 * r];
        const float4* E4 = (const float4*)emb;
        const float4* C4 = (const float4*)cent;
        float s = 0.0f, dot = 0.0f, c2l = 0.0f;
        #pragma unroll
        for (int k = 0; k < 8; ++k) {
            int fo = k * 8 + q * 2;
            float4 u0 = E4[(size_t)r * 64 + fo], u1 = E4[(size_t)r * 64 + fo + 1];
            *(bf16x8*)(Abf + ((size_t)(rb * 8 + k) * 64 + lane) * 16) = pack8(u0, u1);
            s += u0.x*u0.x + u0.y*u0.y + u0.z*u0.z + u0.w*u0.w
               + u1.x*u1.x + u1.y*u1.y + u1.z*u1.z + u1.w*u1.w;
            float4 v0 = C4[lab * 64 + fo], v1 = C4[lab * 64 + fo + 1];
            dot += u0.x*v0.x + u0.y*v0.y + u0.z*v0.z + u0.w*v0.w
                 + u1.x*v1.x + u1.y*v1.y + u1.z*v1.z + u1.w*v1.w;
            c2l += v0.x*v0.x + v0.y*v0.y + v0.z*v0.z + v0.w*v0.w
                 + v1.x*v1.x + v1.y*v1.y + v1.z*v1.z + v1.w*v1.w;
        }
        s += __shfl_xor(s, 16, 64);  s += __shfl_xor(s, 32, 64);
        dot += __shfl_xor(dot, 16, 64); dot += __shfl_xor(dot, 32, 64);
        c2l += __shfl_xor(c2l, 16, 64); c2l += __shfl_xor(c2l, 32, 64);
        if (lane < 16) e2g[rb * 16 + lane] = s;
        float mn = s;
        #pragma unroll
        for (int m = 8; m >= 1; m >>= 1) mn = fminf(mn, __shfl_xor(mn, m, 64));
        float d2 = fmaxf(s + c2l - 2.0f * dot, 0.0f);
        float pos = d2;
        if (d2 < 1.0f) { float t = 1.0f - sqrtf(d2); pos -= t * t; }
        #pragma unroll
        for (int m = 8; m >= 1; m >>= 1) pos += __shfl_xor(pos, m, 64);
        if (lane == 0) {
            atomicMin((int*)e2min, __float_as_int(mn));
            atomicAdd(out, pos * invB);
        }
    }
}

// ---------------- main kernel: A in regs, B double-buffered LDS, MFMA --------
#define CHUNK_BYTES 65536
#define MAIN_SMEM (2 * CHUNK_BYTES + 64)

__global__ __launch_bounds__(512, 2) void main_kernel(
    const char* __restrict__ Abf, const char* __restrict__ Cimg,
    const float* __restrict__ e2g, const float* __restrict__ c2g,
    const unsigned* __restrict__ e2minp, const unsigned* __restrict__ c2minp,
    float* __restrict__ out, int nchunk, float invB) {
    extern __shared__ char smem[];
    char* Bb0 = smem;
    char* Bb1 = smem + CHUNK_BYTES;
    float* red = (float*)(smem + 2 * CHUNK_BYTES);

    const int tid = threadIdx.x, lane = tid & 63, wid = tid >> 6;
    const int wr = wid >> 2, wc = wid & 3;      // 2x4 wave grid, wave tile 64x32
    const int row0 = blockIdx.x * 128;
    const float thresh =
        0.5f * (__uint_as_float(*e2minp) + __uint_as_float(*c2minp) - 1.0f);

    // stage chunk 0 (async, direct to LDS)
    #pragma unroll
    for (int i = 0; i < 8; ++i)
        async_cp16(Cimg + i * 8192 + tid * 16, Bb0 + i * 8192 + wid * 1024);

    // load this wave's A fragments for full K=256 (held across all chunks)
    bf16x8 a[4][8];
    const char* Ab = Abf + (size_t)(row0 / 16 + wr * 4) * 8192;
    #pragma unroll
    for (int m = 0; m < 4; ++m)
        #pragma unroll
        for (int k = 0; k < 8; ++k)
            a[m][k] = *(const bf16x8*)(Ab + m * 8192 + (k * 64 + lane) * 16);

    float fsum = 0.0f;
    asm volatile("s_waitcnt vmcnt(0)" ::: "memory");
    __builtin_amdgcn_s_barrier();

    for (int ch = 0; ch < nchunk; ++ch) {
        const char* Bcur = (ch & 1) ? Bb1 : Bb0;
        char* Bnxt = (ch & 1) ? Bb0 : Bb1;
        if (ch + 1 < nchunk) {
            const char* src = Cimg + (size_t)(ch + 1) * CHUNK_BYTES;
            #pragma unroll
            for (int i = 0; i < 8; ++i)
                async_cp16(src + i * 8192 + tid * 16, Bnxt + i * 8192 + wid * 1024);
        }

        f32x4 acc[4][2];
        #pragma unroll
        for (int m = 0; m < 4; ++m) {
            acc[m][0] = (f32x4){0.0f, 0.0f, 0.0f, 0.0f};
            acc[m][1] = (f32x4){0.0f, 0.0f, 0.0f, 0.0f};
        }
        const char* Bw = Bcur + wc * 16384 + lane * 16;
        #pragma unroll
        for (int k = 0; k < 8; ++k) {
            bf16x8 b0 = *(const bf16x8*)(Bw + k * 1024);
            bf16x8 b1 = *(const bf16x8*)(Bw + 8192 + k * 1024);
            #pragma unroll
            for (int m = 0; m < 4; ++m) {
                acc[m][0] = __builtin_amdgcn_mfma_f32_16x16x32_bf16(a[m][k], b0, acc[m][0], 0, 0, 0);
                acc[m][1] = __builtin_amdgcn_mfma_f32_16x16x32_bf16(a[m][k], b1, acc[m][1], 0, 0, 0);
            }
        }

        // conservative screen: any dot big enough that d2 could be < 1?
        float mx = -3.0e38f;
        #pragma unroll
        for (int m = 0; m < 4; ++m)
            #pragma unroll
            for (int n = 0; n < 2; ++n)
                #pragma unroll
                for (int r = 0; r < 4; ++r)
                    mx = fmaxf(mx, acc[m][n][r]);
        if (__any(mx > thresh)) {   // rare/never: exact per-element slow path
            #pragma unroll
            for (int m = 0; m < 4; ++m)
                #pragma unroll
                for (int n = 0; n < 2; ++n)
                    #pragma unroll
                    for (int r = 0; r < 4; ++r) {
                        float dv = acc[m][n][r];
                        int rowg = row0 + wr * 64 + m * 16 + (lane >> 4) * 4 + r;
                        int colg = ch * 128 + wc * 32 + n * 16 + (lane & 15);
                        float d2 = fmaxf(e2g[rowg] + c2g[colg] - 2.0f * dv, 0.0f);
                        if (d2 < 1.0f) { float t = 1.0f - sqrtf(d2); fsum += t * t; }
                    }
        }
        asm volatile("s_waitcnt vmcnt(0)" ::: "memory");
        __builtin_amdgcn_s_barrier();
    }

    #pragma unroll
    for (int m = 32; m >= 1; m >>= 1) fsum += __shfl_xor(fsum, m, 64);
    if (lane == 0) red[wid] = fsum;
    __syncthreads();
    if (tid == 0) {
        float t = 0.0f;
        #pragma unroll
        for (int w = 0; w < 8; ++w) t += red[w];
        atomicAdd(out, t * invB);
    }
}

// ======================= fallback (round-1, verified) ========================
#define FB_THREADS 512
#define FB_SMEM 132672
__device__ int g_lab_is64;

__global__ void fb_detect_kernel(const unsigned* __restrict__ w, int nelem,
                                 float* __restrict__ out, int out_size) {
    __shared__ unsigned red[256];
    unsigned acc = 0;
    for (int i = threadIdx.x; i < nelem / 2; i += 256) acc |= w[2 * i + 1];
    red[threadIdx.x] = acc;
    __syncthreads();
    for (int s = 128; s > 0; s >>= 1) {
        if (threadIdx.x < s) red[threadIdx.x] |= red[threadIdx.x + s];
        __syncthreads();
    }
    if (threadIdx.x == 0) g_lab_is64 = (red[0] == 0u) ? 1 : 0;
    for (int i = threadIdx.x; i < out_size; i += 256) out[i] = 0.0f;
}

__global__ __launch_bounds__(FB_THREADS) void fb_loss_kernel(
    const float* __restrict__ emb, const float* __restrict__ cent,
    const int* __restrict__ labw, float* __restrict__ out,
    int nchunk, float invB) {
    extern __shared__ char smem[];
    char* Abf = smem;
    char* Cbf = smem + 65536;
    float* e2 = (float*)(smem + 131072);
    float* c2 = (float*)(smem + 131584);
    int* lab = (int*)(smem + 132096);
    float* red = (float*)(smem + 132608);

    const int tid = threadIdx.x, lane = tid & 63, wid = tid >> 6;
    const int row0 = blockIdx.x * 128;
    const int is64 = g_lab_is64;

    for (int j = 0; j < 16; ++j) {
        int f4 = tid + j * FB_THREADS;
        int r = f4 >> 6, c4 = f4 & 63;
        float4 v = ((const float4*)emb)[(size_t)(row0 + r) * 64 + c4];
        ushort4 h;
        h.x = f2bf(v.x); h.y = f2bf(v.y); h.z = f2bf(v.z); h.w = f2bf(v.w);
        int off = (c4 * 8) ^ ((r & 7) << 4);
        *(ushort4*)(Abf + r * 512 + off) = h;
        float s = v.x*v.x + v.y*v.y + v.z*v.z + v.w*v.w;
        #pragma unroll
        for (int m = 32; m >= 1; m >>= 1) s += __shfl_xor(s, m, 64);
        if (lane == 0) e2[r] = s;
    }
    if (tid < 128) {
        int b = row0 + tid;
        lab[tid] = is64 ? labw[2 * b] : labw[b];
    }
    __syncthreads();

    const int wr = wid >> 1, wc = wid & 1;
    const int l15 = lane & 15, l16 = lane >> 4;
    const int swz = (l15 & 7) << 4;

    float e2v[2][4]; int labv[2][4];
    #pragma unroll
    for (int m = 0; m < 2; ++m)
        #pragma unroll
        for (int r = 0; r < 4; ++r) {
            int rr = wr * 32 + m * 16 + l16 * 4 + r;
            e2v[m][r] = e2[rr]; labv[m][r] = lab[rr];
        }

    float fsum = 0.0f;
    for (int ch = 0; ch < nchunk; ++ch) {
        const float* cbase = cent + (size_t)ch * 128 * 256;
        for (int j = 0; j < 16; ++j) {
            int f4 = tid + j * FB_THREADS;
            int r = f4 >> 6, c4 = f4 & 63;
            float4 v = ((const float4*)cbase)[(size_t)r * 64 + c4];
            ushort4 h;
            h.x = f2bf(v.x); h.y = f2bf(v.y); h.z = f2bf(v.z); h.w = f2bf(v.w);
            int off = (c4 * 8) ^ ((r & 7) << 4);
            *(ushort4*)(Cbf + r * 512 + off) = h;
            float s = v.x*v.x + v.y*v.y + v.z*v.z + v.w*v.w;
            #pragma unroll
            for (int m = 32; m >= 1; m >>= 1) s += __shfl_xor(s, m, 64);
            if (lane == 0) c2[r] = s;
        }
        __syncthreads();

        f32x4 acc[2][4];
        #pragma unroll
        for (int m = 0; m < 2; ++m)
            #pragma unroll
            for (int n = 0; n < 4; ++n) acc[m][n] = (f32x4){0, 0, 0, 0};

        #pragma unroll
        for (int kk = 0; kk < 8; ++kk) {
            int kb = kk * 64 + l16 * 16;
            bf16x8 a[2], b[4];
            #pragma unroll
            for (int m = 0; m < 2; ++m)
                a[m] = *(const bf16x8*)(Abf + (wr * 32 + m * 16 + l15) * 512 + (kb ^ swz));
            #pragma unroll
            for (int n = 0; n < 4; ++n)
                b[n] = *(const bf16x8*)(Cbf + (wc * 64 + n * 16 + l15) * 512 + (kb ^ swz));
            #pragma unroll
            for (int m = 0; m < 2; ++m)
                #pragma unroll
                for (int n = 0; n < 4; ++n)
                    acc[m][n] = __builtin_amdgcn_mfma_f32_16x16x32_bf16(a[m], b[n], acc[m][n], 0, 0, 0);
        }

        float c2v[4]; int colg[4];
        #pragma unroll
        for (int n = 0; n < 4; ++n) {
            int cl = wc * 64 + n * 16 + l15;
            c2v[n] = c2[cl]; colg[n] = ch * 128 + cl;
        }
        unsigned need = 0;
        #pragma unroll
        for (int m = 0; m < 2; ++m)
            #pragma unroll
            for (int n = 0; n < 4; ++n)
                #pragma unroll
                for (int r = 0; r < 4; ++r) {
                    float d2 = fmaf(-2.0f, acc[m][n][r], e2v[m][r] + c2v[n]);
                    d2 = fmaxf(d2, 0.0f);
                    bool isp = (colg[n] == labv[m][r]);
                    fsum += isp ? d2 : 0.0f;
                    need |= (unsigned)((!isp) & (d2 < 1.0f)) << (m * 16 + n * 4 + r);
                }
        if (__any(need != 0)) {
            #pragma unroll
            for (int m = 0; m < 2; ++m)
                #pragma unroll
                for (int n = 0; n < 4; ++n)
                    #pragma unroll
                    for (int r = 0; r < 4; ++r)
                        if ((need >> (m * 16 + n * 4 + r)) & 1u) {
                            float d2 = fmaf(-2.0f, acc[m][n][r], e2v[m][r] + c2v[n]);
                            d2 = fmaxf(d2, 0.0f);
                            float t = 1.0f - sqrtf(d2);
                            fsum += t * t;
                        }
        }
        __syncthreads();
    }
    #pragma unroll
    for (int m = 32; m >= 1; m >>= 1) fsum += __shfl_xor(fsum, m, 64);
    if (lane == 0) red[wid] = fsum;
    __syncthreads();
    if (tid == 0) {
        float t = 0.0f;
        #pragma unroll
        for (int w = 0; w < 8; ++w) t += red[w];
        atomicAdd(out, t * invB);
    }
}

// =============================================================================
extern "C" void kernel_launch(void* const* d_in, const int* in_sizes, int n_in,
                              void* d_out, int out_size, void* d_ws, size_t ws_size,
                              hipStream_t stream) {
    const float* emb = (const float*)d_in[0];
    const float* cent = (const float*)d_in[1];
    const int* labw = (const int*)d_in[2];
    float* out = (float*)d_out;

    const int B = in_sizes[0] / 256;
    const int K = in_sizes[1] / 256;
    const int nchunk = K / 128;
    const float invB = 1.0f / (float)B;

    char* ws = (char*)d_ws;
    const size_t off_flag = 0, off_c2min = 64, off_e2min = 128, off_c2 = 256;
    const size_t off_e2 = 8192;
    const size_t off_cimg = off_e2 + (size_t)B * 4;
    const size_t off_abf = (off_cimg + (size_t)K * 512 + 1023) & ~(size_t)1023;
    const size_t req = off_abf + (size_t)B * 512;

    if (ws_size >= req) {
        init_detect_kernel<<<1, 64, 0, stream>>>(
            (const unsigned*)d_in[2], in_sizes[2], (unsigned*)(ws + off_flag),
            (unsigned*)(ws + off_e2min), (unsigned*)(ws + off_c2min), out, out_size);

        const int ncb = K / 64;               // centroid blocks (16)
        prep_kernel<<<ncb + B / 64, 256, 0, stream>>>(
            emb, cent, labw, (const unsigned*)(ws + off_flag),
            ws + off_cimg, (float*)(ws + off_c2), (unsigned*)(ws + off_c2min),
            ws + off_abf, (float*)(ws + off_e2), (unsigned*)(ws + off_e2min),
            out, invB, ncb);

        hipFuncSetAttribute(reinterpret_cast<const void*>(main_kernel),
                            hipFuncAttributeMaxDynamicSharedMemorySize, MAIN_SMEM);
        main_kernel<<<B / 128, 512, MAIN_SMEM, stream>>>(
            ws + off_abf, ws + off_cimg, (const float*)(ws + off_e2),
            (const float*)(ws + off_c2), (const unsigned*)(ws + off_e2min),
            (const unsigned*)(ws + off_c2min), out, nchunk, invB);
    } else {
        fb_detect_kernel<<<1, 256, 0, stream>>>((const unsigned*)d_in[2], in_sizes[2],
                                                out, out_size);
        hipFuncSetAttribute(reinterpret_cast<const void*>(fb_loss_kernel),
                            hipFuncAttributeMaxDynamicSharedMemorySize, FB_SMEM);
        fb_loss_kernel<<<B / 128, FB_THREADS, FB_SMEM, stream>>>(
            emb, cent, labw, out, nchunk, invB);
    }
}

// Round 4
// 67.486 us; speedup vs baseline: 1.6030x; 1.0956x over previous
//
#include <hip/hip_runtime.h>
#include <hip/hip_bf16.h>
#include <math.h>

typedef short bf16x8 __attribute__((ext_vector_type(8)));
typedef float f32x4  __attribute__((ext_vector_type(4)));

static __device__ __forceinline__ unsigned short f2bf(float x) {
    unsigned u = __builtin_bit_cast(unsigned, x);
    return (unsigned short)((u + 0x7fffu + ((u >> 16) & 1u)) >> 16);
}

static __device__ __forceinline__ bf16x8 pack8(float4 u0, float4 u1) {
    bf16x8 f;
    f[0] = (short)f2bf(u0.x); f[1] = (short)f2bf(u0.y);
    f[2] = (short)f2bf(u0.z); f[3] = (short)f2bf(u0.w);
    f[4] = (short)f2bf(u1.x); f[5] = (short)f2bf(u1.y);
    f[6] = (short)f2bf(u1.z); f[7] = (short)f2bf(u1.w);
    return f;
}

static __device__ __forceinline__ void async_cp16(const void* gsrc, void* ldsdst) {
    __builtin_amdgcn_global_load_lds(
        (const __attribute__((address_space(1))) void*)gsrc,
        (__attribute__((address_space(3))) void*)ldsdst, 16, 0, 0);
}

// ---- centroid image + c2 + (block 64: label-width detect + zero out) --------
// img[cb16][k][lane][j] = cent[cb16*16 + (lane&15)][k*32 + (lane>>4)*8 + j]
__global__ __launch_bounds__(64) void cent_prep_kernel(
    const float* __restrict__ cent, char* __restrict__ Cimg,
    float* __restrict__ c2g, const unsigned* __restrict__ w, int nelem,
    unsigned* __restrict__ flag, float* __restrict__ out, int out_size, int ncb) {
    const int lane = threadIdx.x;
    if ((int)blockIdx.x < ncb) {
        const int cb = blockIdx.x;
        const int r = cb * 16 + (lane & 15);
        const int q = lane >> 4;
        const float4* C4 = (const float4*)cent;
        float s = 0.0f;
        #pragma unroll
        for (int k = 0; k < 8; ++k) {
            int fidx = r * 64 + k * 8 + q * 2;
            float4 u0 = C4[fidx], u1 = C4[fidx + 1];
            *(bf16x8*)(Cimg + ((size_t)(cb * 8 + k) * 64 + lane) * 16) = pack8(u0, u1);
            s += u0.x*u0.x + u0.y*u0.y + u0.z*u0.z + u0.w*u0.w
               + u1.x*u1.x + u1.y*u1.y + u1.z*u1.z + u1.w*u1.w;
        }
        s += __shfl_xor(s, 16, 64);
        s += __shfl_xor(s, 32, 64);
        if (lane < 16) c2g[cb * 16 + lane] = s;
    } else {
        // detect label width (sample first 4096 pairs) + zero the output
        int npairs = nelem / 2; if (npairs > 4096) npairs = 4096;
        unsigned acc = 0;
        for (int i = lane; i < npairs; i += 64) acc |= w[2 * i + 1];
        #pragma unroll
        for (int m = 32; m >= 1; m >>= 1) acc |= __shfl_xor(acc, m, 64);
        if (lane == 0) *flag = (acc != 0u) ? 1u : 0u;   // 1 = int32
        for (int i = lane; i < out_size; i += 64) out[i] = 0.0f;
    }
}

// ---- main: A fp32->reg-bf16 in-kernel, B double-buffered LDS, MFMA, epilogue -
#define CHUNK_BYTES 65536
// LDS: Bb0 @0, Bb1 @65536, c2l @131072 (4KB), e2l @135168 (512B),
//      lab @135680 (512B), red @136192 (64B)
#define MAIN_SMEM 136256

__global__ __launch_bounds__(512, 2) void main2_kernel(
    const float* __restrict__ emb, const char* __restrict__ Cimg,
    const float* __restrict__ c2g, const int* __restrict__ labw,
    const unsigned* __restrict__ flag, float* __restrict__ out,
    int nchunk, float invB) {
    extern __shared__ char smem[];
    char*  Bb0 = smem;
    char*  Bb1 = smem + CHUNK_BYTES;
    float* c2l = (float*)(smem + 131072);
    float* e2l = (float*)(smem + 135168);
    int*   lab = (int*)(smem + 135680);
    float* red = (float*)(smem + 136192);

    const int tid = threadIdx.x, lane = tid & 63, wid = tid >> 6;
    const int wr = wid >> 2, wc = wid & 3;      // 2x4 wave grid, wave tile 64x32
    const int row0 = blockIdx.x * 128;
    const int l15 = lane & 15, q = lane >> 4;

    // stage chunk 0 of the centroid image (async, direct to LDS)
    #pragma unroll
    for (int i = 0; i < 8; ++i)
        async_cp16(Cimg + i * 8192 + tid * 16, Bb0 + i * 8192 + wid * 1024);

    // c2 -> LDS (1024 floats)
    c2l[tid] = c2g[tid];
    c2l[tid + 512] = c2g[tid + 512];
    // labels -> LDS (both widths)
    if (tid < 128) {
        int b = row0 + tid;
        lab[tid] = (*flag != 0u) ? labw[b] : labw[2 * b];
    }

    // A: load fp32 directly, convert to MFMA fragments in registers; e2 via shfl.
    // (waves with the same wr duplicate these reads; L2 absorbs the re-reads)
    bf16x8 a[4][8];
    #pragma unroll
    for (int m = 0; m < 4; ++m) {
        const int rg = row0 + wr * 64 + m * 16 + l15;
        const float4* E4 = (const float4*)emb + (size_t)rg * 64;
        float s = 0.0f;
        #pragma unroll
        for (int k = 0; k < 8; ++k) {
            float4 u0 = E4[k * 8 + q * 2], u1 = E4[k * 8 + q * 2 + 1];
            a[m][k] = pack8(u0, u1);
            s += u0.x*u0.x + u0.y*u0.y + u0.z*u0.z + u0.w*u0.w
               + u1.x*u1.x + u1.y*u1.y + u1.z*u1.z + u1.w*u1.w;
        }
        s += __shfl_xor(s, 16, 64);
        s += __shfl_xor(s, 32, 64);
        if (wc == 0 && lane < 16) e2l[wr * 64 + m * 16 + lane] = s;
    }

    float fsum = 0.0f;
    __syncthreads();   // drains async chunk0 + LDS writes

    for (int ch = 0; ch < nchunk; ++ch) {
        const char* Bcur = (ch & 1) ? Bb1 : Bb0;
        char* Bnxt = (ch & 1) ? Bb0 : Bb1;
        if (ch + 1 < nchunk) {
            const char* src = Cimg + (size_t)(ch + 1) * CHUNK_BYTES;
            #pragma unroll
            for (int i = 0; i < 8; ++i)
                async_cp16(src + i * 8192 + tid * 16, Bnxt + i * 8192 + wid * 1024);
        }

        f32x4 acc[4][2];
        #pragma unroll
        for (int m = 0; m < 4; ++m) {
            acc[m][0] = (f32x4){0.0f, 0.0f, 0.0f, 0.0f};
            acc[m][1] = (f32x4){0.0f, 0.0f, 0.0f, 0.0f};
        }
        const char* Bw = Bcur + wc * 16384 + lane * 16;
        #pragma unroll
        for (int k = 0; k < 8; ++k) {
            bf16x8 b0 = *(const bf16x8*)(Bw + k * 1024);
            bf16x8 b1 = *(const bf16x8*)(Bw + 8192 + k * 1024);
            #pragma unroll
            for (int m = 0; m < 4; ++m) {
                acc[m][0] = __builtin_amdgcn_mfma_f32_16x16x32_bf16(a[m][k], b0, acc[m][0], 0, 0, 0);
                acc[m][1] = __builtin_amdgcn_mfma_f32_16x16x32_bf16(a[m][k], b1, acc[m][1], 0, 0, 0);
            }
        }

        // ---- epilogue: pos term + margin screen per element ----
        float c2v[2]; int colg[2];
        #pragma unroll
        for (int n = 0; n < 2; ++n) {
            int cl = wc * 32 + n * 16 + l15;
            c2v[n] = c2l[ch * 128 + cl];
            colg[n] = ch * 128 + cl;
        }
        unsigned need = 0;
        #pragma unroll
        for (int m = 0; m < 4; ++m)
            #pragma unroll
            for (int r = 0; r < 4; ++r) {
                int rl = wr * 64 + m * 16 + q * 4 + r;
                float e2r = e2l[rl];
                int   lbr = lab[rl];
                #pragma unroll
                for (int n = 0; n < 2; ++n) {
                    float d2 = fmaf(-2.0f, acc[m][n][r], e2r + c2v[n]);
                    d2 = fmaxf(d2, 0.0f);
                    bool isp = (colg[n] == lbr);
                    fsum += isp ? d2 : 0.0f;
                    need |= (unsigned)((!isp) & (d2 < 1.0f)) << (m * 8 + r * 2 + n);
                }
            }
        if (__any(need != 0)) {   // rare: a non-label distance < MARGIN
            #pragma unroll
            for (int m = 0; m < 4; ++m)
                #pragma unroll
                for (int r = 0; r < 4; ++r) {
                    int rl = wr * 64 + m * 16 + q * 4 + r;
                    float e2r = e2l[rl];
                    #pragma unroll
                    for (int n = 0; n < 2; ++n)
                        if ((need >> (m * 8 + r * 2 + n)) & 1u) {
                            float d2 = fmaf(-2.0f, acc[m][n][r], e2r + c2v[n]);
                            d2 = fmaxf(d2, 0.0f);
                            float t = 1.0f - sqrtf(d2);
                            fsum += t * t;
                        }
                }
        }
        asm volatile("s_waitcnt vmcnt(0)" ::: "memory");
        __builtin_amdgcn_s_barrier();
    }

    #pragma unroll
    for (int m = 32; m >= 1; m >>= 1) fsum += __shfl_xor(fsum, m, 64);
    if (lane == 0) red[wid] = fsum;
    __syncthreads();
    if (tid == 0) {
        float t = 0.0f;
        #pragma unroll
        for (int w = 0; w < 8; ++w) t += red[w];
        atomicAdd(out, t * invB);
    }
}

// ======================= fallback (round-1, verified) ========================
#define FB_THREADS 512
#define FB_SMEM 132672
__device__ int g_lab_is64;

__global__ void fb_detect_kernel(const unsigned* __restrict__ w, int nelem,
                                 float* __restrict__ out, int out_size) {
    __shared__ unsigned red[256];
    unsigned acc = 0;
    for (int i = threadIdx.x; i < nelem / 2; i += 256) acc |= w[2 * i + 1];
    red[threadIdx.x] = acc;
    __syncthreads();
    for (int s = 128; s > 0; s >>= 1) {
        if (threadIdx.x < s) red[threadIdx.x] |= red[threadIdx.x + s];
        __syncthreads();
    }
    if (threadIdx.x == 0) g_lab_is64 = (red[0] == 0u) ? 1 : 0;
    for (int i = threadIdx.x; i < out_size; i += 256) out[i] = 0.0f;
}

__global__ __launch_bounds__(FB_THREADS) void fb_loss_kernel(
    const float* __restrict__ emb, const float* __restrict__ cent,
    const int* __restrict__ labw, float* __restrict__ out,
    int nchunk, float invB) {
    extern __shared__ char smem[];
    char* Abf = smem;
    char* Cbf = smem + 65536;
    float* e2 = (float*)(smem + 131072);
    float* c2 = (float*)(smem + 131584);
    int* lab = (int*)(smem + 132096);
    float* red = (float*)(smem + 132608);

    const int tid = threadIdx.x, lane = tid & 63, wid = tid >> 6;
    const int row0 = blockIdx.x * 128;
    const int is64 = g_lab_is64;

    for (int j = 0; j < 16; ++j) {
        int f4 = tid + j * FB_THREADS;
        int r = f4 >> 6, c4 = f4 & 63;
        float4 v = ((const float4*)emb)[(size_t)(row0 + r) * 64 + c4];
        ushort4 h;
        h.x = f2bf(v.x); h.y = f2bf(v.y); h.z = f2bf(v.z); h.w = f2bf(v.w);
        int off = (c4 * 8) ^ ((r & 7) << 4);
        *(ushort4*)(Abf + r * 512 + off) = h;
        float s = v.x*v.x + v.y*v.y + v.z*v.z + v.w*v.w;
        #pragma unroll
        for (int m = 32; m >= 1; m >>= 1) s += __shfl_xor(s, m, 64);
        if (lane == 0) e2[r] = s;
    }
    if (tid < 128) {
        int b = row0 + tid;
        lab[tid] = is64 ? labw[2 * b] : labw[b];
    }
    __syncthreads();

    const int wr = wid >> 1, wc = wid & 1;
    const int l15 = lane & 15, l16 = lane >> 4;
    const int swz = (l15 & 7) << 4;

    float e2v[2][4]; int labv[2][4];
    #pragma unroll
    for (int m = 0; m < 2; ++m)
        #pragma unroll
        for (int r = 0; r < 4; ++r) {
            int rr = wr * 32 + m * 16 + l16 * 4 + r;
            e2v[m][r] = e2[rr]; labv[m][r] = lab[rr];
        }

    float fsum = 0.0f;
    for (int ch = 0; ch < nchunk; ++ch) {
        const float* cbase = cent + (size_t)ch * 128 * 256;
        for (int j = 0; j < 16; ++j) {
            int f4 = tid + j * FB_THREADS;
            int r = f4 >> 6, c4 = f4 & 63;
            float4 v = ((const float4*)cbase)[(size_t)r * 64 + c4];
            ushort4 h;
            h.x = f2bf(v.x); h.y = f2bf(v.y); h.z = f2bf(v.z); h.w = f2bf(v.w);
            int off = (c4 * 8) ^ ((r & 7) << 4);
            *(ushort4*)(Cbf + r * 512 + off) = h;
            float s = v.x*v.x + v.y*v.y + v.z*v.z + v.w*v.w;
            #pragma unroll
            for (int m = 32; m >= 1; m >>= 1) s += __shfl_xor(s, m, 64);
            if (lane == 0) c2[r] = s;
        }
        __syncthreads();

        f32x4 acc[2][4];
        #pragma unroll
        for (int m = 0; m < 2; ++m)
            #pragma unroll
            for (int n = 0; n < 4; ++n) acc[m][n] = (f32x4){0, 0, 0, 0};

        #pragma unroll
        for (int kk = 0; kk < 8; ++kk) {
            int kb = kk * 64 + l16 * 16;
            bf16x8 a[2], b[4];
            #pragma unroll
            for (int m = 0; m < 2; ++m)
                a[m] = *(const bf16x8*)(Abf + (wr * 32 + m * 16 + l15) * 512 + (kb ^ swz));
            #pragma unroll
            for (int n = 0; n < 4; ++n)
                b[n] = *(const bf16x8*)(Cbf + (wc * 64 + n * 16 + l15) * 512 + (kb ^ swz));
            #pragma unroll
            for (int m = 0; m < 2; ++m)
                #pragma unroll
                for (int n = 0; n < 4; ++n)
                    acc[m][n] = __builtin_amdgcn_mfma_f32_16x16x32_bf16(a[m], b[n], acc[m][n], 0, 0, 0);
        }

        float c2v[4]; int colg[4];
        #pragma unroll
        for (int n = 0; n < 4; ++n) {
            int cl = wc * 64 + n * 16 + l15;
            c2v[n] = c2[cl]; colg[n] = ch * 128 + cl;
        }
        unsigned need = 0;
        #pragma unroll
        for (int m = 0; m < 2; ++m)
            #pragma unroll
            for (int n = 0; n < 4; ++n)
                #pragma unroll
                for (int r = 0; r < 4; ++r) {
                    float d2 = fmaf(-2.0f, acc[m][n][r], e2v[m][r] + c2v[n]);
                    d2 = fmaxf(d2, 0.0f);
                    bool isp = (colg[n] == labv[m][r]);
                    fsum += isp ? d2 : 0.0f;
                    need |= (unsigned)((!isp) & (d2 < 1.0f)) << (m * 16 + n * 4 + r);
                }
        if (__any(need != 0)) {
            #pragma unroll
            for (int m = 0; m < 2; ++m)
                #pragma unroll
                for (int n = 0; n < 4; ++n)
                    #pragma unroll
                    for (int r = 0; r < 4; ++r)
                        if ((need >> (m * 16 + n * 4 + r)) & 1u) {
                            float d2 = fmaf(-2.0f, acc[m][n][r], e2v[m][r] + c2v[n]);
                            d2 = fmaxf(d2, 0.0f);
                            float t = 1.0f - sqrtf(d2);
                            fsum += t * t;
                        }
        }
        __syncthreads();
    }
    #pragma unroll
    for (int m = 32; m >= 1; m >>= 1) fsum += __shfl_xor(fsum, m, 64);
    if (lane == 0) red[wid] = fsum;
    __syncthreads();
    if (tid == 0) {
        float t = 0.0f;
        #pragma unroll
        for (int w = 0; w < 8; ++w) t += red[w];
        atomicAdd(out, t * invB);
    }
}

// =============================================================================
extern "C" void kernel_launch(void* const* d_in, const int* in_sizes, int n_in,
                              void* d_out, int out_size, void* d_ws, size_t ws_size,
                              hipStream_t stream) {
    const float* emb = (const float*)d_in[0];
    const float* cent = (const float*)d_in[1];
    const int* labw = (const int*)d_in[2];
    float* out = (float*)d_out;

    const int B = in_sizes[0] / 256;
    const int K = in_sizes[1] / 256;
    const int nchunk = K / 128;
    const float invB = 1.0f / (float)B;

    char* ws = (char*)d_ws;
    const size_t off_flag = 0;
    const size_t off_c2 = 256;
    const size_t off_cimg = 8192;
    const size_t req = off_cimg + (size_t)K * 512;

    if (ws_size >= req) {
        const int ncb = K / 16;               // 64 centroid-image blocks
        cent_prep_kernel<<<ncb + 1, 64, 0, stream>>>(
            cent, ws + off_cimg, (float*)(ws + off_c2),
            (const unsigned*)d_in[2], in_sizes[2], (unsigned*)(ws + off_flag),
            out, out_size, ncb);

        hipFuncSetAttribute(reinterpret_cast<const void*>(main2_kernel),
                            hipFuncAttributeMaxDynamicSharedMemorySize, MAIN_SMEM);
        main2_kernel<<<B / 128, 512, MAIN_SMEM, stream>>>(
            emb, ws + off_cimg, (const float*)(ws + off_c2), labw,
            (const unsigned*)(ws + off_flag), out, nchunk, invB);
    } else {
        fb_detect_kernel<<<1, 256, 0, stream>>>((const unsigned*)d_in[2], in_sizes[2],
                                                out, out_size);
        hipFuncSetAttribute(reinterpret_cast<const void*>(fb_loss_kernel),
                            hipFuncAttributeMaxDynamicSharedMemorySize, FB_SMEM);
        fb_loss_kernel<<<B / 128, FB_THREADS, FB_SMEM, stream>>>(
            emb, cent, labw, out, nchunk, invB);
    }
}